// Round 5
// baseline (517.620 us; speedup 1.0000x reference)
//
#include <hip/hip_runtime.h>
#include <math.h>

// Problem constants
#define BB   64
#define CIN  16
#define LL   8192
#define CO   32
#define TCO  64
constexpr int T0n = 128;   // frames for n=64
constexpr int T1n = 32;    // frames for n=256
constexpr int F0n = 33;
constexpr int F1n = 129;

typedef unsigned int   uint32;
typedef unsigned short u16;
typedef __attribute__((ext_vector_type(8))) _Float16 half8;  // 8 f16 (4 VGPRs)
typedef __attribute__((ext_vector_type(4))) float    f32x4;  // MFMA accumulator
typedef __attribute__((ext_vector_type(4))) uint32   u32x4;

__device__ inline int imin(int a, int b) { return a < b ? a : b; }

// sign-flip pattern (+,+,-,-,+,+,-,-) over a half8 B-frag: k2 = 8a+j -> f = 4a+(j>>1),
// (-1)^f over j flips j=2,3,6,7 = dwords 1 and 3.  Used for W row symmetry:
// W[m+N/2][k2] = (-1)^{f(k2)} * W[m][k2].
__device__ inline half8 flip_pm(half8 v) {
    u32x4 u;
    __builtin_memcpy(&u, &v, 16);
    u.y ^= 0x80008000u;
    u.w ^= 0x80008000u;
    half8 r;
    __builtin_memcpy(&r, &u, 16);
    return r;
}

// ---------------- STFT as GEMM: spec[t][j] = sum_k X[t][k] * D[k][j] -----------
template<int N, int F, int TFR, int NTILES, int KTT, int MT_W, int NT_W,
         int NT_STRIDE, bool MT_SPLIT>
__global__ __launch_bounds__(256)
void stft_mfma_kernel(const float* __restrict__ x,
                      const u16* __restrict__ dhi, const u16* __restrict__ dlo,
                      float* __restrict__ p) {
    constexpr int PADN = N + 8;            // +16B row pad -> 2-way LDS alias (free)
    __shared__ __align__(16) u16 Xhi[TFR * PADN];
    __shared__ __align__(16) u16 Xlo[TFR * PADN];
    int bc = blockIdx.x;                   // b*CIN + c
    const float* xrow = x + (size_t)bc * LL;

    for (int i = threadIdx.x; i < TFR * N; i += 256) {
        int row = i / N, colk = i % N;
        int gi = i - N / 2;                // xp[i] = x[i - N/2], reflect left
        gi = gi < 0 ? -gi : gi;
        float v = xrow[gi];
        _Float16 h = (_Float16)v;
        _Float16 l = (_Float16)(v - (float)h);
        Xhi[row * PADN + colk] = *(u16*)&h;
        Xlo[row * PADN + colk] = *(u16*)&l;
    }
    __syncthreads();

    int lane = threadIdx.x & 63, w = threadIdx.x >> 6;
    int col = lane & 15, quad = lane >> 4;
    f32x4 acc[MT_W][NT_W];
    #pragma unroll
    for (int mi = 0; mi < MT_W; ++mi)
        #pragma unroll
        for (int nj = 0; nj < NT_W; ++nj) {
            f32x4 z = {0.f, 0.f, 0.f, 0.f};
            acc[mi][nj] = z;
        }

    for (int kt = 0; kt < KTT; ++kt) {
        half8 ah[MT_W], al[MT_W];
        #pragma unroll
        for (int mi = 0; mi < MT_W; ++mi) {
            int mt = MT_SPLIT ? (w * MT_W + mi) : mi;
            int t  = mt * 16 + col;
            ah[mi] = *(const half8*)&Xhi[t * PADN + kt * 32 + quad * 8];
            al[mi] = *(const half8*)&Xlo[t * PADN + kt * 32 + quad * 8];
        }
        #pragma unroll
        for (int nj = 0; nj < NT_W; ++nj) {
            int nt = MT_SPLIT ? nj : (w + nj * NT_STRIDE);
            if (nt < NTILES) {
                half8 bh = ((const half8*)dhi)[(nt * KTT + kt) * 64 + lane];
                half8 bl = ((const half8*)dlo)[(nt * KTT + kt) * 64 + lane];
                #pragma unroll
                for (int mi = 0; mi < MT_W; ++mi) {
                    acc[mi][nj] = __builtin_amdgcn_mfma_f32_16x16x32_f16(ah[mi], bh, acc[mi][nj], 0, 0, 0);
                    acc[mi][nj] = __builtin_amdgcn_mfma_f32_16x16x32_f16(ah[mi], bl, acc[mi][nj], 0, 0, 0);
                    acc[mi][nj] = __builtin_amdgcn_mfma_f32_16x16x32_f16(al[mi], bh, acc[mi][nj], 0, 0, 0);
                }
            }
        }
    }

    int b = bc / CIN, c = bc % CIN;
    #pragma unroll
    for (int mi = 0; mi < MT_W; ++mi) {
        int mt = MT_SPLIT ? (w * MT_W + mi) : mi;
        #pragma unroll
        for (int nj = 0; nj < NT_W; ++nj) {
            int nt = MT_SPLIT ? nj : (w + nj * NT_STRIDE);
            if (nt < NTILES) {
                int j = nt * 16 + col;
                if (j < 2 * F) {
                    int t0 = mt * 16 + quad * 4;
                    f32x4 a = acc[mi][nj];
                    #pragma unroll
                    for (int r = 0; r < 4; ++r) {
                        p[(((size_t)b * TFR + t0 + r) * CIN + c) * (2 * F) + j] = a[r];
                    }
                }
            }
        }
    }
}

// ---------------- init: STFT D tables, B-fragment order, split fp16 ------------
__global__ __launch_bounds__(256)
void init_d_kernel(u16* __restrict__ dhi0, u16* __restrict__ dlo0,
                   u16* __restrict__ dhi1, u16* __restrict__ dlo1) {
    int idx = blockIdx.x * 256 + threadIdx.x;
    constexpr int SZ0 = 5 * 2 * 64 * 8;    // 5120
    constexpr int SZ1 = 17 * 8 * 64 * 8;   // 69632
    int N, F, KTT, id; u16 *dh, *dl;
    if (idx < SZ0)            { N = 64;  F = F0n; KTT = 2; dh = dhi0; dl = dlo0; id = idx; }
    else if (idx < SZ0 + SZ1) { N = 256; F = F1n; KTT = 8; dh = dhi1; dl = dlo1; id = idx - SZ0; }
    else return;
    int jj   = id & 7;
    int lane = (id >> 3) & 63;
    int rest = id >> 9;
    int kt   = rest % KTT;
    int nt   = rest / KTT;
    int j = nt * 16 + (lane & 15);
    int k = kt * 32 + (lane >> 4) * 8 + jj;
    float v = 0.f;
    if (j < 2 * F) {
        int f = j >> 1;
        int u = (f * k) % N;
        double th = 6.283185307179586476925286766559 * (double)u / (double)N;
        v = (float)((j & 1) ? -sin(th) : cos(th));
    }
    _Float16 h = (_Float16)v;
    _Float16 l = (_Float16)(v - (float)h);
    dh[id] = *(u16*)&h;
    dl[id] = *(u16*)&l;
}

// ---------------- merge (attention over 4 sub-frames), in-place into p1 --------
__global__ __launch_bounds__(256)
void merge_kernel(const float2* __restrict__ p0, float2* __restrict__ p1,
                  const float* __restrict__ mkr, const float* __restrict__ mki,
                  const float* __restrict__ mbr, const float* __restrict__ mbi) {
    int idx = blockIdx.x * 256 + threadIdx.x;
    const int total = BB * T1n * CIN * F0n;
    if (idx >= total) return;
    int f0 = idx % F0n; int r1 = idx / F0n;
    int c  = r1 % CIN;  int r2 = r1 / CIN;
    int t1 = r2 % T1n;  int b  = r2 / T1n;
    float2 pm[4];
    #pragma unroll
    for (int r = 0; r < 4; ++r) {
        int t = t1 * 4 + r;
        pm[r] = p0[(((size_t)b * T0n + t) * CIN + c) * F0n + f0];
    }
    float mag[4], mx = -1e30f;
    #pragma unroll
    for (int s = 0; s < 4; ++s) {
        float atr = mbr[s], ati = mbi[s];
        #pragma unroll
        for (int r = 0; r < 4; ++r) {
            float kr = mkr[r * 4 + s], ki = mki[r * 4 + s];
            atr = fmaf(pm[r].x, kr, atr); atr = fmaf(-pm[r].y, ki, atr);
            ati = fmaf(pm[r].x, ki, ati); ati = fmaf(pm[r].y, kr, ati);
        }
        mag[s] = sqrtf(atr * atr + ati * ati);
        mx = fmaxf(mx, mag[s]);
    }
    float se = 0.f;
    #pragma unroll
    for (int s = 0; s < 4; ++s) { mag[s] = expf(mag[s] - mx); se += mag[s]; }
    float inv = 4.0f / se;                 // RATIO / sum
    float mr = 0.f, mi = 0.f;
    #pragma unroll
    for (int r = 0; r < 4; ++r) { mr = fmaf(pm[r].x, mag[r], mr); mi = fmaf(pm[r].y, mag[r], mi); }
    p1[(((size_t)b * T1n + t1) * CIN + c) * F1n + 4 * f0] = make_float2(mr * inv, mi * inv);
}

// ---------------- complex batch-norm stats, two-stage ---------------------------
__global__ __launch_bounds__(256)
void cbn_partial_kernel(const float2* __restrict__ p0, const float2* __restrict__ p1,
                        float4* __restrict__ part) {
    int blk  = blockIdx.x;                 // head*512 + b*8 + c8
    int c8   = blk & 7;
    int b    = (blk >> 3) & 63;
    int head = blk >> 9;
    int Nel  = head ? (T1n * CIN * F1n) : (T0n * CIN * F0n);
    const float2* base = head ? (p1 + (size_t)b * (T1n * CIN * F1n))
                              : (p0 + (size_t)b * (T0n * CIN * F0n));
    int chunk = (Nel + 7) / 8;
    int i0 = c8 * chunk, i1 = imin(i0 + chunk, Nel);
    float sr = 0.f, si = 0.f, s2 = 0.f;
    for (int i = i0 + threadIdx.x; i < i1; i += 256) {
        float2 v = base[i];
        sr += v.x; si += v.y;
        s2 = fmaf(v.x, v.x, s2); s2 = fmaf(v.y, v.y, s2);
    }
    __shared__ float red[3][256];
    red[0][threadIdx.x] = sr; red[1][threadIdx.x] = si; red[2][threadIdx.x] = s2;
    __syncthreads();
    for (int off = 128; off > 0; off >>= 1) {
        if (threadIdx.x < off) {
            red[0][threadIdx.x] += red[0][threadIdx.x + off];
            red[1][threadIdx.x] += red[1][threadIdx.x + off];
            red[2][threadIdx.x] += red[2][threadIdx.x + off];
        }
        __syncthreads();
    }
    if (threadIdx.x == 0)
        part[blk] = make_float4(red[0][0], red[1][0], red[2][0], 0.f);
}

__global__ __launch_bounds__(128)
void cbn_final_kernel(const float4* __restrict__ part,
                      const float* __restrict__ gamma, const float* __restrict__ beta,
                      float4* __restrict__ bn) {
    int hb = threadIdx.x;                  // 0..127 = head*64 + b
    float sr = 0.f, si = 0.f, s2 = 0.f;
    #pragma unroll
    for (int c = 0; c < 8; ++c) {
        float4 v = part[hb * 8 + c];
        sr += v.x; si += v.y; s2 += v.z;
    }
    int head = hb >> 6;
    int Nel  = head ? (T1n * CIN * F1n) : (T0n * CIN * F0n);
    float invN = 1.f / (float)Nel;
    float mur = sr * invN, mui = si * invN;
    float var = s2 * invN - mur * mur - mui * mui;
    float g = gamma[hb] * rsqrtf(var + 1e-5f);
    bn[hb] = make_float4(g, beta[hb] - mur * g, -mui * g, 0.f);
}

// ---------------- init: irfft twiddle matrix (HALF rows m < N/2), split fp16 ---
__global__ __launch_bounds__(256)
void init_w_kernel(u16* __restrict__ whi0, u16* __restrict__ wlo0,
                   u16* __restrict__ whi1, u16* __restrict__ wlo1) {
    int idx = blockIdx.x * 256 + threadIdx.x;
    constexpr int SZ0 = 2 * 3 * 64 * 8;    // 3072
    constexpr int SZ1 = 8 * 9 * 64 * 8;    // 36864
    int N, F, KT, id; u16 *dh, *dl;
    if (idx < SZ0)            { N = 64;  F = F0n; KT = 3; dh = whi0; dl = wlo0; id = idx; }
    else if (idx < SZ0 + SZ1) { N = 256; F = F1n; KT = 9; dh = whi1; dl = wlo1; id = idx - SZ0; }
    else return;
    int j    = id & 7;
    int lane = (id >> 3) & 63;
    int rest = id >> 9;
    int kt   = rest % KT;
    int mt   = rest / KT;
    int m  = mt * 16 + (lane & 15);        // m < N/2 only
    int k2 = kt * 32 + (lane >> 4) * 8 + j;
    float v = 0.f;
    if (k2 < 2 * F) {
        int f = k2 >> 1;
        double scale = (f == 0 || f == F - 1) ? (1024.0 / N) : (2048.0 / N);
        int u = (m * f) % N;
        double th = 6.283185307179586476925286766559 * (double)u / (double)N;
        v = (float)((k2 & 1) ? (-scale * sin(th)) : (scale * cos(th)));
    }
    _Float16 h = (_Float16)v;
    _Float16 l = (_Float16)(v - (float)h);
    dh[id] = *(u16*)&h;
    dl[id] = *(u16*)&l;
}

// ---------------- init: fk tables, layout i = o*F + f (coalesced S stores) -----
// fkq[c2*FCO + o*F + f] = (kr(f,2c2,o), ki(f,2c2,o), kr(f,2c2+1,o), ki(f,2c2+1,o))
// fks[o*F + f] = sum_ci (kr, ki)
__global__ __launch_bounds__(256)
void init_fk_kernel(const float* __restrict__ r0, const float* __restrict__ i0,
                    const float* __restrict__ r1, const float* __restrict__ i1,
                    float4* __restrict__ q0, float4* __restrict__ q1,
                    float2* __restrict__ s0, float2* __restrict__ s1) {
    int idx = blockIdx.x * 256 + threadIdx.x;
    constexpr int NQ0 = 8 * F0n * 32;   // 8448
    constexpr int NQ1 = 8 * F1n * 32;   // 33024
    constexpr int NS0 = F0n * 32;       // 1056
    constexpr int NS1 = F1n * 32;       // 4128
    if (idx < NQ0) {
        int id = idx;
        int c2 = id / (F0n * 32); int rem = id % (F0n * 32);
        int o = rem / F0n, f = rem % F0n;
        int s = (f * CIN + 2 * c2) * CO + o;
        q0[id] = make_float4(r0[s], i0[s], r0[s + CO], i0[s + CO]);
    } else if (idx < NQ0 + NQ1) {
        int id = idx - NQ0;
        int c2 = id / (F1n * 32); int rem = id % (F1n * 32);
        int o = rem / F1n, f = rem % F1n;
        int s = (f * CIN + 2 * c2) * CO + o;
        q1[id] = make_float4(r1[s], i1[s], r1[s + CO], i1[s + CO]);
    } else if (idx < NQ0 + NQ1 + NS0) {
        int id = idx - NQ0 - NQ1;
        int o = id / F0n, f = id % F0n;
        float sr = 0.f, si = 0.f;
        for (int ci = 0; ci < CIN; ++ci) {
            int s = (f * CIN + ci) * CO + o;
            sr += r0[s]; si += i0[s];
        }
        s0[id] = make_float2(sr, si);
    } else if (idx < NQ0 + NQ1 + NS0 + NS1) {
        int id = idx - NQ0 - NQ1 - NS0;
        int o = id / F1n, f = id % F1n;
        float sr = 0.f, si = 0.f;
        for (int ci = 0; ci < CIN; ++ci) {
            int s = (f * CIN + ci) * CO + o;
            sr += r1[s]; si += i1[s];
        }
        s1[id] = make_float2(sr, si);
    }
}

// ---------------- einsum: CBN-folded, frame-batched, writes PACKED S -----------
// S global layout (per frame): [o][dword f] in Ghi (re_lo16|im_hi16 of f16-hi)
// and Glo (f16-lo residuals) — exactly the Shi/Slo LDS layout irfft wants.
// Pads f in [F, PADW) zeroed here so irfft staging is a pure copy.
template<int F, int TFR, int CH0, int G, int PADW>
__global__ __launch_bounds__(256)
void einsum_kernel(const float2* __restrict__ p, const float4* __restrict__ fkq,
                   const float2* __restrict__ fks, const float4* __restrict__ bn,
                   uint32* __restrict__ Ghi, uint32* __restrict__ Glo) {
    constexpr int FCO = F * 32;
    constexpr int NG  = TFR / G;
    __shared__ float2 xs[G][CIN * F];
    int grp = blockIdx.x % NG, b = blockIdx.x / NG;
    float4 par = bn[(CH0 ? 1 : 0) * BB + b];   // (g, t_re, t_im, -)
    {
        const float4* a4 = (const float4*)(p + ((size_t)b * TFR + (size_t)grp * G) * CIN * F);
        float4* x4 = (float4*)&xs[0][0];
        for (int i = threadIdx.x; i < G * CIN * F / 2; i += 256) x4[i] = a4[i];
    }
    __syncthreads();
    size_t bt0 = (size_t)b * TFR + (size_t)grp * G;
    for (int i = threadIdx.x; i < FCO; i += 256) {
        int o = i / F, f = i - o * F;
        float4 kk[8];
        #pragma unroll
        for (int c2 = 0; c2 < 8; ++c2) kk[c2] = fkq[c2 * FCO + i];  // coalesced
        float2 fv = fks[i];
        float base_re = fmaf(par.y, fv.x, -par.z * fv.y);
        float base_im = fmaf(par.y, fv.y,  par.z * fv.x);
        #pragma unroll
        for (int g = 0; g < G; ++g) {
            float re = 0.f, im = 0.f;
            #pragma unroll
            for (int c2 = 0; c2 < 8; ++c2) {
                float2 xa = xs[g][(2 * c2) * F + f];
                float2 xb = xs[g][(2 * c2 + 1) * F + f];
                float4 kkc = kk[c2];
                re = fmaf(xa.x, kkc.x, re); re = fmaf(-xa.y, kkc.y, re);
                im = fmaf(xa.x, kkc.y, im); im = fmaf(xa.y, kkc.x, im);
                re = fmaf(xb.x, kkc.z, re); re = fmaf(-xb.y, kkc.w, re);
                im = fmaf(xb.x, kkc.w, im); im = fmaf(xb.y, kkc.z, im);
            }
            float res = fmaf(par.x, re, base_re) * 32.f;
            float ims = fmaf(par.x, im, base_im) * 32.f;
            _Float16 rh = (_Float16)res; _Float16 rl = (_Float16)(res - (float)rh);
            _Float16 ih = (_Float16)ims; _Float16 il = (_Float16)(ims - (float)ih);
            size_t d = ((bt0 + g) * 32 + o) * PADW + f;
            Ghi[d] = ((uint32)(*(u16*)&ih) << 16) | (uint32)(*(u16*)&rh);
            Glo[d] = ((uint32)(*(u16*)&il) << 16) | (uint32)(*(u16*)&rl);
        }
    }
    constexpr int PADC = PADW - F;
    for (int j = threadIdx.x; j < G * 32 * PADC; j += 256) {
        int g = j / (32 * PADC); int r = j - g * (32 * PADC);
        int o = r / PADC;        int c = r - o * PADC;
        size_t d = ((bt0 + g) * 32 + o) * PADW + F + c;
        Ghi[d] = 0; Glo[d] = 0;
    }
}

// ---------------- irfft: frame-looping, T14 async stage, W row-symmetry --------
// Block = (b, chunk of FRC frames).  Per frame: out[l][ch] = sum_k2 W*S (split f16,
// Wh*Sh+Wh*Sl+Wl*Sh).  Stage of frame ft+1 issued to regs BEFORE frame ft's MFMA
// (HBM latency hides under MFMA), ds-written after the reads-done barrier.
// LDS rows padded to LDW=KT*16+4 dwords (stride%32=20 -> 2-way alias, free).
template<int N, int F, int TFR, int CH0, int KT, int FRC, int WMT, bool NTSPLIT>
__global__ __launch_bounds__(256)
void irfft_kernel(const uint32* __restrict__ Ghi, const uint32* __restrict__ Glo,
                  const u16* __restrict__ whi, const u16* __restrict__ wlo,
                  const float* __restrict__ pbias, float* __restrict__ out) {
    constexpr int PADW = KT * 16;          // global row dwords
    constexpr int LDW  = PADW + 4;         // LDS row dwords (bank-spread)
    constexpr int RW4  = PADW / 4;         // float4 per row
    constexpr int NLD  = (32 * RW4 + 255) / 256;
    constexpr int NCH  = (TFR + 1 + FRC - 1) / FRC;
    constexpr int WNT  = NTSPLIT ? 1 : 2;
    __shared__ __align__(16) uint32 buf[2][32 * LDW];   // [hi/lo][row*LDW+..]

    int ch = blockIdx.x % NCH, b = blockIdx.x / NCH;
    int ft0 = ch * FRC, ftend = imin(ft0 + FRC, TFR + 1);
    int lane = threadIdx.x & 63, w = threadIdx.x >> 6;
    int col = lane & 15, quad = lane >> 4;

    float4 rh[NLD], rl[NLD];
    auto stage_load = [&](int ft) {
        int tf = (ft == TFR) ? 0 : ft;
        const float4* sH = (const float4*)(Ghi + ((size_t)b * TFR + tf) * 32 * PADW);
        const float4* sL = (const float4*)(Glo + ((size_t)b * TFR + tf) * 32 * PADW);
        #pragma unroll
        for (int q = 0; q < NLD; ++q) {
            int i = threadIdx.x + q * 256;
            if (i < 32 * RW4) { rh[q] = sH[i]; rl[q] = sL[i]; }
        }
    };
    auto stage_write = [&]() {
        #pragma unroll
        for (int q = 0; q < NLD; ++q) {
            int i = threadIdx.x + q * 256;
            if (i < 32 * RW4) {
                int row = i / RW4, c = i - row * RW4;
                *(float4*)&buf[0][row * LDW + 4 * c] = rh[q];
                *(float4*)&buf[1][row * LDW + 4 * c] = rl[q];
            }
        }
    };

    stage_load(ft0);
    stage_write();
    __syncthreads();

    const u16* bufh = (const u16*)&buf[0][0];
    const u16* bufl = (const u16*)&buf[1][0];
    constexpr float UNSCALE = 1.0f / 32768.0f;   // 2^-15 (W*2^10, S*2^5)
    size_t bb = (size_t)b * TCO;

    for (int ft = ft0; ft < ftend; ++ft) {
        bool nxt = (ft + 1 < ftend);
        if (nxt) stage_load(ft + 1);           // latency hides under MFMA below

        f32x4 accB[WMT][WNT], accD[WMT][WNT];
        #pragma unroll
        for (int mi = 0; mi < WMT; ++mi)
            #pragma unroll
            for (int nj = 0; nj < WNT; ++nj) {
                f32x4 z = {0.f, 0.f, 0.f, 0.f};
                accB[mi][nj] = z; accD[mi][nj] = z;
            }
        for (int kt = 0; kt < KT; ++kt) {
            half8 bh[WNT], bl[WNT], bhm[WNT], blm[WNT];
            #pragma unroll
            for (int nj = 0; nj < WNT; ++nj) {
                int nt = NTSPLIT ? (w & 1) : nj;
                int ro = (nt * 16 + col) * (2 * LDW) + kt * 32 + quad * 8;
                bh[nj]  = *(const half8*)(bufh + ro);
                bl[nj]  = *(const half8*)(bufl + ro);
                bhm[nj] = flip_pm(bh[nj]);
                blm[nj] = flip_pm(bl[nj]);
            }
            #pragma unroll
            for (int mi = 0; mi < WMT; ++mi) {
                int mt = NTSPLIT ? (w >> 1) : (w * WMT + mi);
                half8 ah = ((const half8*)whi)[(mt * KT + kt) * 64 + lane];
                half8 al = ((const half8*)wlo)[(mt * KT + kt) * 64 + lane];
                #pragma unroll
                for (int nj = 0; nj < WNT; ++nj) {
                    accB[mi][nj] = __builtin_amdgcn_mfma_f32_16x16x32_f16(ah, bh[nj],  accB[mi][nj], 0, 0, 0);
                    accB[mi][nj] = __builtin_amdgcn_mfma_f32_16x16x32_f16(ah, bl[nj],  accB[mi][nj], 0, 0, 0);
                    accB[mi][nj] = __builtin_amdgcn_mfma_f32_16x16x32_f16(al, bh[nj],  accB[mi][nj], 0, 0, 0);
                    accD[mi][nj] = __builtin_amdgcn_mfma_f32_16x16x32_f16(ah, bhm[nj], accD[mi][nj], 0, 0, 0);
                    accD[mi][nj] = __builtin_amdgcn_mfma_f32_16x16x32_f16(ah, blm[nj], accD[mi][nj], 0, 0, 0);
                    accD[mi][nj] = __builtin_amdgcn_mfma_f32_16x16x32_f16(al, bhm[nj], accD[mi][nj], 0, 0, 0);
                }
            }
        }
        // epilogue for frame ft
        #pragma unroll
        for (int mi = 0; mi < WMT; ++mi) {
            int mt = NTSPLIT ? (w >> 1) : (w * WMT + mi);
            #pragma unroll
            for (int hh = 0; hh < 2; ++hh) {
                int m  = mt * 16 + quad * 4 + hh * (N / 2);
                int l0 = ft * N + m - N / 2;
                if ((unsigned)l0 < LL) {
                    #pragma unroll
                    for (int nj = 0; nj < WNT; ++nj) {
                        int nt = NTSPLIT ? (w & 1) : nj;
                        int chn = CH0 + nt * 16 + col;
                        float pb = pbias[chn];
                        f32x4 a = hh ? accD[mi][nj] : accB[mi][nj];
                        float4 v;
                        v.x = fmaxf(fmaf(a[0], UNSCALE, pb), 0.f);
                        v.y = fmaxf(fmaf(a[1], UNSCALE, pb), 0.f);
                        v.z = fmaxf(fmaf(a[2], UNSCALE, pb), 0.f);
                        v.w = fmaxf(fmaf(a[3], UNSCALE, pb), 0.f);
                        *(float4*)(out + (bb + chn) * LL + l0) = v;
                    }
                }
            }
        }
        __syncthreads();                       // all reads of buf done
        if (nxt) stage_write();
        __syncthreads();                       // writes visible before next MFMA
    }
}

extern "C" void kernel_launch(void* const* d_in, const int* in_sizes, int n_in,
                              void* d_out, int out_size, void* d_ws, size_t ws_size,
                              hipStream_t stream) {
    const float* x     = (const float*)d_in[0];
    const float* gam   = (const float*)d_in[1];
    const float* bet   = (const float*)d_in[2];
    const float* mkr   = (const float*)d_in[3];
    const float* mki   = (const float*)d_in[4];
    const float* mbr   = (const float*)d_in[5];
    const float* mbi   = (const float*)d_in[6];
    const float* fk0r  = (const float*)d_in[7];
    const float* fk0i  = (const float*)d_in[8];
    const float* fk1r  = (const float*)d_in[9];
    const float* fk1i  = (const float*)d_in[10];
    const float* pbias = (const float*)d_in[11];
    float* out = (float*)d_out;

    float2* p0   = (float2*)d_ws;                                   // 34.6 MB
    float2* p1   = p0 + (size_t)BB * T0n * CIN * F0n;               // 33.8 MB
    float4* bnp  = (float4*)(p1 + (size_t)BB * T1n * CIN * F1n);    // 2 KB
    float4* part = bnp + 2 * BB;                                    // 16 KB
    float4* fkq0 = part + 1024;                                     // 135 KB
    float4* fkq1 = fkq0 + 8 * F0n * 32;                             // 528 KB
    float2* fks0 = (float2*)(fkq1 + 8 * F1n * 32);                  // 8 KB
    float2* fks1 = fks0 + F0n * 32;                                 // 33 KB
    uint32* Ghi  = (uint32*)(fks1 + F1n * 32);                      // 50.3 MB
    uint32* Glo  = Ghi + (size_t)8192 * 32 * 48;                    // 50.3 MB
    u16*    whi0 = (u16*)(Glo + (size_t)8192 * 32 * 48);            // 6 KB
    u16*    wlo0 = whi0 + 3072;
    u16*    whi1 = wlo0 + 3072;                                     // 72 KB
    u16*    wlo1 = whi1 + 36864;
    u16*    dhi0 = wlo1 + 36864;                                    // 10 KB
    u16*    dlo0 = dhi0 + 5120;
    u16*    dhi1 = dlo0 + 5120;                                     // 139 KB
    u16*    dlo1 = dhi1 + 69632;

    init_w_kernel<<<(3072 + 36864 + 255) / 256, 256, 0, stream>>>(whi0, wlo0, whi1, wlo1);
    init_d_kernel<<<(5120 + 69632 + 255) / 256, 256, 0, stream>>>(dhi0, dlo0, dhi1, dlo1);
    init_fk_kernel<<<(8 * (F0n + F1n) * 32 + (F0n + F1n) * 32 + 255) / 256, 256, 0, stream>>>(
        fk0r, fk0i, fk1r, fk1i, fkq0, fkq1, fks0, fks1);
    stft_mfma_kernel<64, F0n, 128, 5, 2, 2, 5, 1, true><<<BB * CIN, 256, 0, stream>>>(
        x, dhi0, dlo0, (float*)p0);
    stft_mfma_kernel<256, F1n, 32, 17, 8, 2, 5, 4, false><<<BB * CIN, 256, 0, stream>>>(
        x, dhi1, dlo1, (float*)p1);
    merge_kernel<<<(BB * T1n * CIN * F0n) / 256, 256, 0, stream>>>(p0, p1, mkr, mki, mbr, mbi);
    cbn_partial_kernel<<<1024, 256, 0, stream>>>(p0, p1, part);
    cbn_final_kernel<<<1, 128, 0, stream>>>(part, gam, bet, bnp);
    // head1 then head0, sharing Ghi/Glo (stream order makes reuse safe)
    einsum_kernel<F1n, T1n, 32, 4, 144><<<BB * (T1n / 4), 256, 0, stream>>>(
        p1, fkq1, fks1, bnp, Ghi, Glo);
    irfft_kernel<256, F1n, T1n, 32, 9, 9, 2, false><<<BB * 4, 256, 0, stream>>>(
        Ghi, Glo, whi1, wlo1, pbias, out);
    einsum_kernel<F0n, T0n, 0, 8, 48><<<BB * (T0n / 8), 256, 0, stream>>>(
        p0, fkq0, fks0, bnp, Ghi, Glo);
    irfft_kernel<64, F0n, T0n, 0, 3, 17, 1, true><<<BB * 8, 256, 0, stream>>>(
        Ghi, Glo, whi0, wlo0, pbias, out);
}

// Round 6
// 503.648 us; speedup vs baseline: 1.0277x; 1.0277x over previous
//
#include <hip/hip_runtime.h>
#include <math.h>

// Problem constants
#define BB   64
#define CIN  16
#define LL   8192
#define CO   32
#define TCO  64
constexpr int T0n = 128;   // frames for n=64
constexpr int T1n = 32;    // frames for n=256
constexpr int F0n = 33;
constexpr int F1n = 129;

typedef unsigned int   uint32;
typedef unsigned short u16;
typedef __attribute__((ext_vector_type(8))) _Float16 half8;  // 8 f16 (4 VGPRs)
typedef __attribute__((ext_vector_type(4))) float    f32x4;  // MFMA accumulator
typedef __attribute__((ext_vector_type(4))) uint32   u32x4;

__device__ inline int imin(int a, int b) { return a < b ? a : b; }

// sign-flip pattern (+,+,-,-,+,+,-,-) over a half8 B-frag: k2 = 8a+j -> f = 4a+(j>>1),
// (-1)^f over j flips j=2,3,6,7 = dwords 1 and 3.  Used for W row symmetry:
// W[m+N/2][k2] = (-1)^{f(k2)} * W[m][k2].  (correctness-proven in the 468us run)
__device__ inline half8 flip_pm(half8 v) {
    u32x4 u;
    __builtin_memcpy(&u, &v, 16);
    u.y ^= 0x80008000u;
    u.w ^= 0x80008000u;
    half8 r;
    __builtin_memcpy(&r, &u, 16);
    return r;
}

// ---------------- STFT as GEMM: spec[t][j] = sum_k X[t][k] * D[k][j] -----------
template<int N, int F, int TFR, int NTILES, int KTT, int MT_W, int NT_W,
         int NT_STRIDE, bool MT_SPLIT>
__global__ __launch_bounds__(256)
void stft_mfma_kernel(const float* __restrict__ x,
                      const u16* __restrict__ dhi, const u16* __restrict__ dlo,
                      float* __restrict__ p) {
    constexpr int PADN = N + 8;            // +16B row pad -> 2-way LDS alias (free)
    __shared__ __align__(16) u16 Xhi[TFR * PADN];
    __shared__ __align__(16) u16 Xlo[TFR * PADN];
    int bc = blockIdx.x;                   // b*CIN + c
    const float* xrow = x + (size_t)bc * LL;

    for (int i = threadIdx.x; i < TFR * N; i += 256) {
        int row = i / N, colk = i % N;
        int gi = i - N / 2;                // xp[i] = x[i - N/2], reflect left
        gi = gi < 0 ? -gi : gi;
        float v = xrow[gi];
        _Float16 h = (_Float16)v;
        _Float16 l = (_Float16)(v - (float)h);
        Xhi[row * PADN + colk] = *(u16*)&h;
        Xlo[row * PADN + colk] = *(u16*)&l;
    }
    __syncthreads();

    int lane = threadIdx.x & 63, w = threadIdx.x >> 6;
    int col = lane & 15, quad = lane >> 4;
    f32x4 acc[MT_W][NT_W];
    #pragma unroll
    for (int mi = 0; mi < MT_W; ++mi)
        #pragma unroll
        for (int nj = 0; nj < NT_W; ++nj) {
            f32x4 z = {0.f, 0.f, 0.f, 0.f};
            acc[mi][nj] = z;
        }

    for (int kt = 0; kt < KTT; ++kt) {
        half8 ah[MT_W], al[MT_W];
        #pragma unroll
        for (int mi = 0; mi < MT_W; ++mi) {
            int mt = MT_SPLIT ? (w * MT_W + mi) : mi;
            int t  = mt * 16 + col;
            ah[mi] = *(const half8*)&Xhi[t * PADN + kt * 32 + quad * 8];
            al[mi] = *(const half8*)&Xlo[t * PADN + kt * 32 + quad * 8];
        }
        #pragma unroll
        for (int nj = 0; nj < NT_W; ++nj) {
            int nt = MT_SPLIT ? nj : (w + nj * NT_STRIDE);
            if (nt < NTILES) {
                half8 bh = ((const half8*)dhi)[(nt * KTT + kt) * 64 + lane];
                half8 bl = ((const half8*)dlo)[(nt * KTT + kt) * 64 + lane];
                #pragma unroll
                for (int mi = 0; mi < MT_W; ++mi) {
                    acc[mi][nj] = __builtin_amdgcn_mfma_f32_16x16x32_f16(ah[mi], bh, acc[mi][nj], 0, 0, 0);
                    acc[mi][nj] = __builtin_amdgcn_mfma_f32_16x16x32_f16(ah[mi], bl, acc[mi][nj], 0, 0, 0);
                    acc[mi][nj] = __builtin_amdgcn_mfma_f32_16x16x32_f16(al[mi], bh, acc[mi][nj], 0, 0, 0);
                }
            }
        }
    }

    int b = bc / CIN, c = bc % CIN;
    #pragma unroll
    for (int mi = 0; mi < MT_W; ++mi) {
        int mt = MT_SPLIT ? (w * MT_W + mi) : mi;
        #pragma unroll
        for (int nj = 0; nj < NT_W; ++nj) {
            int nt = MT_SPLIT ? nj : (w + nj * NT_STRIDE);
            if (nt < NTILES) {
                int j = nt * 16 + col;
                if (j < 2 * F) {
                    int t0 = mt * 16 + quad * 4;
                    f32x4 a = acc[mi][nj];
                    #pragma unroll
                    for (int r = 0; r < 4; ++r) {
                        p[(((size_t)b * TFR + t0 + r) * CIN + c) * (2 * F) + j] = a[r];
                    }
                }
            }
        }
    }
}

// ---------------- init: STFT D tables, B-fragment order, split fp16 ------------
__global__ __launch_bounds__(256)
void init_d_kernel(u16* __restrict__ dhi0, u16* __restrict__ dlo0,
                   u16* __restrict__ dhi1, u16* __restrict__ dlo1) {
    int idx = blockIdx.x * 256 + threadIdx.x;
    constexpr int SZ0 = 5 * 2 * 64 * 8;    // 5120
    constexpr int SZ1 = 17 * 8 * 64 * 8;   // 69632
    int N, F, KTT, id; u16 *dh, *dl;
    if (idx < SZ0)            { N = 64;  F = F0n; KTT = 2; dh = dhi0; dl = dlo0; id = idx; }
    else if (idx < SZ0 + SZ1) { N = 256; F = F1n; KTT = 8; dh = dhi1; dl = dlo1; id = idx - SZ0; }
    else return;
    int jj   = id & 7;
    int lane = (id >> 3) & 63;
    int rest = id >> 9;
    int kt   = rest % KTT;
    int nt   = rest / KTT;
    int j = nt * 16 + (lane & 15);
    int k = kt * 32 + (lane >> 4) * 8 + jj;
    float v = 0.f;
    if (j < 2 * F) {
        int f = j >> 1;
        int u = (f * k) % N;
        double th = 6.283185307179586476925286766559 * (double)u / (double)N;
        v = (float)((j & 1) ? -sin(th) : cos(th));
    }
    _Float16 h = (_Float16)v;
    _Float16 l = (_Float16)(v - (float)h);
    dh[id] = *(u16*)&h;
    dl[id] = *(u16*)&l;
}

// ---------------- merge (attention over 4 sub-frames), in-place into p1 --------
__global__ __launch_bounds__(256)
void merge_kernel(const float2* __restrict__ p0, float2* __restrict__ p1,
                  const float* __restrict__ mkr, const float* __restrict__ mki,
                  const float* __restrict__ mbr, const float* __restrict__ mbi) {
    int idx = blockIdx.x * 256 + threadIdx.x;
    const int total = BB * T1n * CIN * F0n;
    if (idx >= total) return;
    int f0 = idx % F0n; int r1 = idx / F0n;
    int c  = r1 % CIN;  int r2 = r1 / CIN;
    int t1 = r2 % T1n;  int b  = r2 / T1n;
    float2 pm[4];
    #pragma unroll
    for (int r = 0; r < 4; ++r) {
        int t = t1 * 4 + r;
        pm[r] = p0[(((size_t)b * T0n + t) * CIN + c) * F0n + f0];
    }
    float mag[4], mx = -1e30f;
    #pragma unroll
    for (int s = 0; s < 4; ++s) {
        float atr = mbr[s], ati = mbi[s];
        #pragma unroll
        for (int r = 0; r < 4; ++r) {
            float kr = mkr[r * 4 + s], ki = mki[r * 4 + s];
            atr = fmaf(pm[r].x, kr, atr); atr = fmaf(-pm[r].y, ki, atr);
            ati = fmaf(pm[r].x, ki, ati); ati = fmaf(pm[r].y, kr, ati);
        }
        mag[s] = sqrtf(atr * atr + ati * ati);
        mx = fmaxf(mx, mag[s]);
    }
    float se = 0.f;
    #pragma unroll
    for (int s = 0; s < 4; ++s) { mag[s] = expf(mag[s] - mx); se += mag[s]; }
    float inv = 4.0f / se;                 // RATIO / sum
    float mr = 0.f, mi = 0.f;
    #pragma unroll
    for (int r = 0; r < 4; ++r) { mr = fmaf(pm[r].x, mag[r], mr); mi = fmaf(pm[r].y, mag[r], mi); }
    p1[(((size_t)b * T1n + t1) * CIN + c) * F1n + 4 * f0] = make_float2(mr * inv, mi * inv);
}

// ---------------- complex batch-norm stats, two-stage ---------------------------
__global__ __launch_bounds__(256)
void cbn_partial_kernel(const float2* __restrict__ p0, const float2* __restrict__ p1,
                        float4* __restrict__ part) {
    int blk  = blockIdx.x;                 // head*512 + b*8 + c8
    int c8   = blk & 7;
    int b    = (blk >> 3) & 63;
    int head = blk >> 9;
    int Nel  = head ? (T1n * CIN * F1n) : (T0n * CIN * F0n);
    const float2* base = head ? (p1 + (size_t)b * (T1n * CIN * F1n))
                              : (p0 + (size_t)b * (T0n * CIN * F0n));
    int chunk = (Nel + 7) / 8;
    int i0 = c8 * chunk, i1 = imin(i0 + chunk, Nel);
    float sr = 0.f, si = 0.f, s2 = 0.f;
    for (int i = i0 + threadIdx.x; i < i1; i += 256) {
        float2 v = base[i];
        sr += v.x; si += v.y;
        s2 = fmaf(v.x, v.x, s2); s2 = fmaf(v.y, v.y, s2);
    }
    __shared__ float red[3][256];
    red[0][threadIdx.x] = sr; red[1][threadIdx.x] = si; red[2][threadIdx.x] = s2;
    __syncthreads();
    for (int off = 128; off > 0; off >>= 1) {
        if (threadIdx.x < off) {
            red[0][threadIdx.x] += red[0][threadIdx.x + off];
            red[1][threadIdx.x] += red[1][threadIdx.x + off];
            red[2][threadIdx.x] += red[2][threadIdx.x + off];
        }
        __syncthreads();
    }
    if (threadIdx.x == 0)
        part[blk] = make_float4(red[0][0], red[1][0], red[2][0], 0.f);
}

__global__ __launch_bounds__(128)
void cbn_final_kernel(const float4* __restrict__ part,
                      const float* __restrict__ gamma, const float* __restrict__ beta,
                      float4* __restrict__ bn) {
    int hb = threadIdx.x;                  // 0..127 = head*64 + b
    float sr = 0.f, si = 0.f, s2 = 0.f;
    #pragma unroll
    for (int c = 0; c < 8; ++c) {
        float4 v = part[hb * 8 + c];
        sr += v.x; si += v.y; s2 += v.z;
    }
    int head = hb >> 6;
    int Nel  = head ? (T1n * CIN * F1n) : (T0n * CIN * F0n);
    float invN = 1.f / (float)Nel;
    float mur = sr * invN, mui = si * invN;
    float var = s2 * invN - mur * mur - mui * mui;
    float g = gamma[hb] * rsqrtf(var + 1e-5f);
    bn[hb] = make_float4(g, beta[hb] - mur * g, -mui * g, 0.f);
}

// ---------------- init: irfft twiddle matrix (HALF rows m < N/2), split fp16 ---
__global__ __launch_bounds__(256)
void init_w_kernel(u16* __restrict__ whi0, u16* __restrict__ wlo0,
                   u16* __restrict__ whi1, u16* __restrict__ wlo1) {
    int idx = blockIdx.x * 256 + threadIdx.x;
    constexpr int SZ0 = 2 * 3 * 64 * 8;    // 3072
    constexpr int SZ1 = 8 * 9 * 64 * 8;    // 36864
    int N, F, KT, id; u16 *dh, *dl;
    if (idx < SZ0)            { N = 64;  F = F0n; KT = 3; dh = whi0; dl = wlo0; id = idx; }
    else if (idx < SZ0 + SZ1) { N = 256; F = F1n; KT = 9; dh = whi1; dl = wlo1; id = idx - SZ0; }
    else return;
    int j    = id & 7;
    int lane = (id >> 3) & 63;
    int rest = id >> 9;
    int kt   = rest % KT;
    int mt   = rest / KT;
    int m  = mt * 16 + (lane & 15);        // m < N/2 only
    int k2 = kt * 32 + (lane >> 4) * 8 + j;
    float v = 0.f;
    if (k2 < 2 * F) {
        int f = k2 >> 1;
        double scale = (f == 0 || f == F - 1) ? (1024.0 / N) : (2048.0 / N);
        int u = (m * f) % N;
        double th = 6.283185307179586476925286766559 * (double)u / (double)N;
        v = (float)((k2 & 1) ? (-scale * sin(th)) : (scale * cos(th)));
    }
    _Float16 h = (_Float16)v;
    _Float16 l = (_Float16)(v - (float)h);
    dh[id] = *(u16*)&h;
    dl[id] = *(u16*)&l;
}

// ---------------- init: fk tables, layout i = o*F + f --------------------------
// fkq[c2*FCO + o*F + f] = (kr(f,2c2,o), ki(f,2c2,o), kr(f,2c2+1,o), ki(f,2c2+1,o))
// fks[o*F + f] = sum_ci (kr, ki)
__global__ __launch_bounds__(256)
void init_fk_kernel(const float* __restrict__ r0, const float* __restrict__ i0,
                    const float* __restrict__ r1, const float* __restrict__ i1,
                    float4* __restrict__ q0, float4* __restrict__ q1,
                    float2* __restrict__ s0, float2* __restrict__ s1) {
    int idx = blockIdx.x * 256 + threadIdx.x;
    constexpr int NQ0 = 8 * F0n * 32;   // 8448
    constexpr int NQ1 = 8 * F1n * 32;   // 33024
    constexpr int NS0 = F0n * 32;       // 1056
    constexpr int NS1 = F1n * 32;       // 4128
    if (idx < NQ0) {
        int id = idx;
        int c2 = id / (F0n * 32); int rem = id % (F0n * 32);
        int o = rem / F0n, f = rem % F0n;
        int s = (f * CIN + 2 * c2) * CO + o;
        q0[id] = make_float4(r0[s], i0[s], r0[s + CO], i0[s + CO]);
    } else if (idx < NQ0 + NQ1) {
        int id = idx - NQ0;
        int c2 = id / (F1n * 32); int rem = id % (F1n * 32);
        int o = rem / F1n, f = rem % F1n;
        int s = (f * CIN + 2 * c2) * CO + o;
        q1[id] = make_float4(r1[s], i1[s], r1[s + CO], i1[s + CO]);
    } else if (idx < NQ0 + NQ1 + NS0) {
        int id = idx - NQ0 - NQ1;
        int o = id / F0n, f = id % F0n;
        float sr = 0.f, si = 0.f;
        for (int ci = 0; ci < CIN; ++ci) {
            int s = (f * CIN + ci) * CO + o;
            sr += r0[s]; si += i0[s];
        }
        s0[id] = make_float2(sr, si);
    } else if (idx < NQ0 + NQ1 + NS0 + NS1) {
        int id = idx - NQ0 - NQ1 - NS0;
        int o = id / F1n, f = id % F1n;
        float sr = 0.f, si = 0.f;
        for (int ci = 0; ci < CIN; ++ci) {
            int s = (f * CIN + ci) * CO + o;
            sr += r1[s]; si += i1[s];
        }
        s1[id] = make_float2(sr, si);
    }
}

// ---------------- einsum: weights-in-VGPR streaming form -----------------------
// Block = (f-chunk of FCH, b).  Thread (o, f') holds its 8 fkq float4 in VGPRs
// for the WHOLE kernel (fkq L2 traffic 270MB -> 36MB) and streams bt in
// BTB-frame LDS batches.  Writes packed split-f16 S dwords:
//   Ghi[(bt*32+o)*F + f] = ih<<16|rh,  Glo = il<<16|rl  (S row stride = F, no pad)
template<int F, int TFR, int CH0, int FCH, int BTB>
__global__ __launch_bounds__(256)
void einsum_kernel(const float2* __restrict__ p, const float4* __restrict__ fkq,
                   const float2* __restrict__ fks, const float4* __restrict__ bn,
                   uint32* __restrict__ Ghi, uint32* __restrict__ Glo) {
    constexpr int FCO  = F * 32;
    constexpr int NFCH = (F + FCH - 1) / FCH;
    static_assert(FCH == 8 && BTB * CIN * FCH % 256 == 0, "cfg");
    __shared__ float2 xs[BTB][CIN][FCH];
    int fch = blockIdx.x % NFCH;
    int b   = blockIdx.x / NFCH;
    int f0  = fch * FCH;
    int o   = threadIdx.x >> 3;        // 0..31
    int fl  = threadIdx.x & 7;         // 0..7
    int f   = f0 + fl;
    bool valid = f < F;
    int fc = valid ? f : F - 1;
    float4 kk[8];
    #pragma unroll
    for (int c2 = 0; c2 < 8; ++c2) kk[c2] = fkq[c2 * FCO + o * F + fc];  // coalesced 128B runs
    float2 fv = fks[o * F + fc];
    float4 par = bn[(CH0 ? 1 : 0) * BB + b];   // (g, t_re, t_im, -)
    float base_re = fmaf(par.y, fv.x, -par.z * fv.y);
    float base_im = fmaf(par.y, fv.y,  par.z * fv.x);

    for (int t0 = 0; t0 < TFR; t0 += BTB) {
        const float2* pb = p + (size_t)(b * TFR + t0) * CIN * F;
        for (int i = threadIdx.x; i < BTB * CIN * FCH; i += 256) {
            int fi = i & 7;            // FCH = 8
            int r  = i >> 3;           // t'*CIN + ci
            int ff = f0 + fi;
            ((float2*)xs)[i] = (ff < F) ? pb[(size_t)r * F + ff] : make_float2(0.f, 0.f);
        }
        __syncthreads();
        for (int tp = 0; tp < BTB; ++tp) {
            float re = 0.f, im = 0.f;
            #pragma unroll
            for (int c2 = 0; c2 < 8; ++c2) {
                float2 xa = xs[tp][2 * c2][fl];        // LDS broadcast (32 lanes/addr)
                float2 xb = xs[tp][2 * c2 + 1][fl];
                float4 kkc = kk[c2];
                re = fmaf(xa.x, kkc.x, re); re = fmaf(-xa.y, kkc.y, re);
                im = fmaf(xa.x, kkc.y, im); im = fmaf(xa.y, kkc.x, im);
                re = fmaf(xb.x, kkc.z, re); re = fmaf(-xb.y, kkc.w, re);
                im = fmaf(xb.x, kkc.w, im); im = fmaf(xb.y, kkc.z, im);
            }
            if (valid) {
                float res = fmaf(par.x, re, base_re) * 32.f;
                float ims = fmaf(par.x, im, base_im) * 32.f;
                _Float16 rh = (_Float16)res; _Float16 rl = (_Float16)(res - (float)rh);
                _Float16 ih = (_Float16)ims; _Float16 il = (_Float16)(ims - (float)ih);
                size_t d = ((size_t)(b * TFR + t0 + tp) * 32 + o) * F + f;
                Ghi[d] = ((uint32)(*(u16*)&ih) << 16) | (uint32)(*(u16*)&rh);
                Glo[d] = ((uint32)(*(u16*)&il) << 16) | (uint32)(*(u16*)&rl);
            }
        }
        __syncthreads();
    }
}

// ---------------- irfft: per-frame blocks, copy staging, W row-symmetry --------
// grid: B*(TFR+1); frame TFR re-uses S of frame 0 (wrap frame).
// Stage = pure dword copy (S already packed split-f16 by einsum) + LDS zero-pad
// of columns [F, KT*16).  LDS rows LDW=KT*16+4 dwords (2-way bank alias, free).
// Structure identical to the 468us-proven per-frame irfft.
template<int N, int F, int TFR, int CH0, int KT, int WMT, bool NTSPLIT>
__global__ __launch_bounds__(256)
void irfft_kernel(const uint32* __restrict__ Ghi, const uint32* __restrict__ Glo,
                  const u16* __restrict__ whi, const u16* __restrict__ wlo,
                  const float* __restrict__ pbias, float* __restrict__ out) {
    constexpr int PADW = KT * 16;
    constexpr int LDW  = PADW + 4;
    constexpr int WNT  = NTSPLIT ? 1 : 2;
    __shared__ __align__(16) uint32 buf[2][32 * LDW];
    int t  = blockIdx.x % (TFR + 1);
    int b  = blockIdx.x / (TFR + 1);
    int tf = (t == TFR) ? 0 : t;
    const uint32* sH = Ghi + (size_t)(b * TFR + tf) * 32 * F;
    const uint32* sL = Glo + (size_t)(b * TFR + tf) * 32 * F;
    for (int i = threadIdx.x; i < 32 * F; i += 256) {
        int row = i / F, c = i - row * F;
        buf[0][row * LDW + c] = sH[i];
        buf[1][row * LDW + c] = sL[i];
    }
    for (int i = threadIdx.x; i < 32 * (PADW - F); i += 256) {
        constexpr int cols = PADW - F;
        int row = i / cols, c = i - row * cols;
        buf[0][row * LDW + F + c] = 0;
        buf[1][row * LDW + F + c] = 0;
    }
    __syncthreads();

    int lane = threadIdx.x & 63, w = threadIdx.x >> 6;
    int col = lane & 15, quad = lane >> 4;
    const u16* bufh = (const u16*)&buf[0][0];
    const u16* bufl = (const u16*)&buf[1][0];

    f32x4 accB[WMT][WNT], accD[WMT][WNT];   // base rows m, derived rows m+N/2
    #pragma unroll
    for (int mi = 0; mi < WMT; ++mi)
        #pragma unroll
        for (int nj = 0; nj < WNT; ++nj) {
            f32x4 z = {0.f, 0.f, 0.f, 0.f};
            accB[mi][nj] = z; accD[mi][nj] = z;
        }
    for (int kt = 0; kt < KT; ++kt) {
        half8 bh[WNT], bl[WNT], bhm[WNT], blm[WNT];
        #pragma unroll
        for (int nj = 0; nj < WNT; ++nj) {
            int nt = NTSPLIT ? (w & 1) : nj;
            int ro = (nt * 16 + col) * (2 * LDW) + kt * 32 + quad * 8;
            bh[nj]  = *(const half8*)(bufh + ro);
            bl[nj]  = *(const half8*)(bufl + ro);
            bhm[nj] = flip_pm(bh[nj]);
            blm[nj] = flip_pm(bl[nj]);
        }
        #pragma unroll
        for (int mi = 0; mi < WMT; ++mi) {
            int mt = NTSPLIT ? (w >> 1) : (w * WMT + mi);
            half8 ah = ((const half8*)whi)[(mt * KT + kt) * 64 + lane];
            half8 al = ((const half8*)wlo)[(mt * KT + kt) * 64 + lane];
            #pragma unroll
            for (int nj = 0; nj < WNT; ++nj) {
                accB[mi][nj] = __builtin_amdgcn_mfma_f32_16x16x32_f16(ah, bh[nj],  accB[mi][nj], 0, 0, 0);
                accB[mi][nj] = __builtin_amdgcn_mfma_f32_16x16x32_f16(ah, bl[nj],  accB[mi][nj], 0, 0, 0);
                accB[mi][nj] = __builtin_amdgcn_mfma_f32_16x16x32_f16(al, bh[nj],  accB[mi][nj], 0, 0, 0);
                accD[mi][nj] = __builtin_amdgcn_mfma_f32_16x16x32_f16(ah, bhm[nj], accD[mi][nj], 0, 0, 0);
                accD[mi][nj] = __builtin_amdgcn_mfma_f32_16x16x32_f16(ah, blm[nj], accD[mi][nj], 0, 0, 0);
                accD[mi][nj] = __builtin_amdgcn_mfma_f32_16x16x32_f16(al, bhm[nj], accD[mi][nj], 0, 0, 0);
            }
        }
    }
    constexpr float UNSCALE = 1.0f / 32768.0f;   // 2^-15 (W*2^10, S*2^5)
    size_t bb = (size_t)b * TCO;
    #pragma unroll
    for (int mi = 0; mi < WMT; ++mi) {
        int mt = NTSPLIT ? (w >> 1) : (w * WMT + mi);
        #pragma unroll
        for (int hh = 0; hh < 2; ++hh) {
            int m  = mt * 16 + quad * 4 + hh * (N / 2);
            int l0 = t * N + m - N / 2;
            if ((unsigned)l0 < LL) {
                #pragma unroll
                for (int nj = 0; nj < WNT; ++nj) {
                    int nt = NTSPLIT ? (w & 1) : nj;
                    int chn = CH0 + nt * 16 + col;
                    float pb = pbias[chn];
                    f32x4 a = hh ? accD[mi][nj] : accB[mi][nj];
                    float4 v;
                    v.x = fmaxf(fmaf(a[0], UNSCALE, pb), 0.f);
                    v.y = fmaxf(fmaf(a[1], UNSCALE, pb), 0.f);
                    v.z = fmaxf(fmaf(a[2], UNSCALE, pb), 0.f);
                    v.w = fmaxf(fmaf(a[3], UNSCALE, pb), 0.f);
                    *(float4*)(out + (bb + chn) * LL + l0) = v;
                }
            }
        }
    }
}

extern "C" void kernel_launch(void* const* d_in, const int* in_sizes, int n_in,
                              void* d_out, int out_size, void* d_ws, size_t ws_size,
                              hipStream_t stream) {
    const float* x     = (const float*)d_in[0];
    const float* gam   = (const float*)d_in[1];
    const float* bet   = (const float*)d_in[2];
    const float* mkr   = (const float*)d_in[3];
    const float* mki   = (const float*)d_in[4];
    const float* mbr   = (const float*)d_in[5];
    const float* mbi   = (const float*)d_in[6];
    const float* fk0r  = (const float*)d_in[7];
    const float* fk0i  = (const float*)d_in[8];
    const float* fk1r  = (const float*)d_in[9];
    const float* fk1i  = (const float*)d_in[10];
    const float* pbias = (const float*)d_in[11];
    float* out = (float*)d_out;

    float2* p0   = (float2*)d_ws;                                   // 34.6 MB
    float2* p1   = p0 + (size_t)BB * T0n * CIN * F0n;               // 33.8 MB
    float4* bnp  = (float4*)(p1 + (size_t)BB * T1n * CIN * F1n);    // 2 KB
    float4* part = bnp + 2 * BB;                                    // 16 KB
    float4* fkq0 = part + 1024;                                     // 135 KB
    float4* fkq1 = fkq0 + 8 * F0n * 32;                             // 528 KB
    float2* fks0 = (float2*)(fkq1 + 8 * F1n * 32);                  // 8 KB
    float2* fks1 = fks0 + F0n * 32;                                 // 33 KB
    // S buffers: sized for the larger head (head0: 64*128*32*33 dwords = 34.6 MB)
    uint32* Ghi  = (uint32*)(fks1 + F1n * 32);
    uint32* Glo  = Ghi + (size_t)BB * T0n * 32 * F0n;
    u16*    whi0 = (u16*)(Glo + (size_t)BB * T0n * 32 * F0n);       // 6 KB
    u16*    wlo0 = whi0 + 3072;
    u16*    whi1 = wlo0 + 3072;                                     // 72 KB
    u16*    wlo1 = whi1 + 36864;
    u16*    dhi0 = wlo1 + 36864;                                    // 10 KB
    u16*    dlo0 = dhi0 + 5120;
    u16*    dhi1 = dlo0 + 5120;                                     // 139 KB
    u16*    dlo1 = dhi1 + 69632;

    init_w_kernel<<<(3072 + 36864 + 255) / 256, 256, 0, stream>>>(whi0, wlo0, whi1, wlo1);
    init_d_kernel<<<(5120 + 69632 + 255) / 256, 256, 0, stream>>>(dhi0, dlo0, dhi1, dlo1);
    init_fk_kernel<<<(8 * (F0n + F1n) * 32 + (F0n + F1n) * 32 + 255) / 256, 256, 0, stream>>>(
        fk0r, fk0i, fk1r, fk1i, fkq0, fkq1, fks0, fks1);
    stft_mfma_kernel<64, F0n, 128, 5, 2, 2, 5, 1, true><<<BB * CIN, 256, 0, stream>>>(
        x, dhi0, dlo0, (float*)p0);
    stft_mfma_kernel<256, F1n, 32, 17, 8, 2, 5, 4, false><<<BB * CIN, 256, 0, stream>>>(
        x, dhi1, dlo1, (float*)p1);
    merge_kernel<<<(BB * T1n * CIN * F0n) / 256, 256, 0, stream>>>(p0, p1, mkr, mki, mbr, mbi);
    cbn_partial_kernel<<<1024, 256, 0, stream>>>(p0, p1, part);
    cbn_final_kernel<<<1, 128, 0, stream>>>(part, gam, bet, bnp);
    // head1 then head0, sharing Ghi/Glo (stream order makes reuse safe)
    einsum_kernel<F1n, T1n, 32, 8, 16><<<17 * BB, 256, 0, stream>>>(
        p1, fkq1, fks1, bnp, Ghi, Glo);
    irfft_kernel<256, F1n, T1n, 32, 9, 2, false><<<BB * (T1n + 1), 256, 0, stream>>>(
        Ghi, Glo, whi1, wlo1, pbias, out);
    einsum_kernel<F0n, T0n, 0, 8, 16><<<5 * BB, 256, 0, stream>>>(
        p0, fkq0, fks0, bnp, Ghi, Glo);
    irfft_kernel<64, F0n, T0n, 0, 3, 1, true><<<BB * (T0n + 1), 256, 0, stream>>>(
        Ghi, Glo, whi0, wlo0, pbias, out);
}

// Round 7
// 463.187 us; speedup vs baseline: 1.1175x; 1.0874x over previous
//
#include <hip/hip_runtime.h>
#include <math.h>

// Problem constants
#define BB   64
#define CIN  16
#define LL   8192
#define CO   32
#define TCO  64
constexpr int T0n = 128;   // frames for n=64
constexpr int T1n = 32;    // frames for n=256
constexpr int F0n = 33;
constexpr int F1n = 129;

typedef unsigned int   uint32;
typedef unsigned short u16;
typedef __attribute__((ext_vector_type(8))) _Float16 half8;  // 8 f16 (4 VGPRs)
typedef __attribute__((ext_vector_type(4))) float    f32x4;  // MFMA accumulator
typedef __attribute__((ext_vector_type(4))) uint32   u32x4;

__device__ inline int imin(int a, int b) { return a < b ? a : b; }

// sign-flip pattern (+,+,-,-,+,+,-,-) over a half8 B-frag: k2 = 8a+j -> f = 4a+(j>>1),
// (-1)^f over j flips j=2,3,6,7 = dwords 1 and 3.  Used for W row symmetry:
// W[m+N/2][k2] = (-1)^{f(k2)} * W[m][k2].  (correctness-proven in the 468us run)
__device__ inline half8 flip_pm(half8 v) {
    u32x4 u;
    __builtin_memcpy(&u, &v, 16);
    u.y ^= 0x80008000u;
    u.w ^= 0x80008000u;
    half8 r;
    __builtin_memcpy(&r, &u, 16);
    return r;
}

// ---------------- STFT as GEMM: spec[t][j] = sum_k X[t][k] * D[k][j] -----------
template<int N, int F, int TFR, int NTILES, int KTT, int MT_W, int NT_W,
         int NT_STRIDE, bool MT_SPLIT>
__global__ __launch_bounds__(256)
void stft_mfma_kernel(const float* __restrict__ x,
                      const u16* __restrict__ dhi, const u16* __restrict__ dlo,
                      float* __restrict__ p) {
    constexpr int PADN = N + 8;            // +16B row pad -> 2-way LDS alias (free)
    __shared__ __align__(16) u16 Xhi[TFR * PADN];
    __shared__ __align__(16) u16 Xlo[TFR * PADN];
    int bc = blockIdx.x;                   // b*CIN + c
    const float* xrow = x + (size_t)bc * LL;

    for (int i = threadIdx.x; i < TFR * N; i += 256) {
        int row = i / N, colk = i % N;
        int gi = i - N / 2;                // xp[i] = x[i - N/2], reflect left
        gi = gi < 0 ? -gi : gi;
        float v = xrow[gi];
        _Float16 h = (_Float16)v;
        _Float16 l = (_Float16)(v - (float)h);
        Xhi[row * PADN + colk] = *(u16*)&h;
        Xlo[row * PADN + colk] = *(u16*)&l;
    }
    __syncthreads();

    int lane = threadIdx.x & 63, w = threadIdx.x >> 6;
    int col = lane & 15, quad = lane >> 4;
    f32x4 acc[MT_W][NT_W];
    #pragma unroll
    for (int mi = 0; mi < MT_W; ++mi)
        #pragma unroll
        for (int nj = 0; nj < NT_W; ++nj) {
            f32x4 z = {0.f, 0.f, 0.f, 0.f};
            acc[mi][nj] = z;
        }

    for (int kt = 0; kt < KTT; ++kt) {
        half8 ah[MT_W], al[MT_W];
        #pragma unroll
        for (int mi = 0; mi < MT_W; ++mi) {
            int mt = MT_SPLIT ? (w * MT_W + mi) : mi;
            int t  = mt * 16 + col;
            ah[mi] = *(const half8*)&Xhi[t * PADN + kt * 32 + quad * 8];
            al[mi] = *(const half8*)&Xlo[t * PADN + kt * 32 + quad * 8];
        }
        #pragma unroll
        for (int nj = 0; nj < NT_W; ++nj) {
            int nt = MT_SPLIT ? nj : (w + nj * NT_STRIDE);
            if (nt < NTILES) {
                half8 bh = ((const half8*)dhi)[(nt * KTT + kt) * 64 + lane];
                half8 bl = ((const half8*)dlo)[(nt * KTT + kt) * 64 + lane];
                #pragma unroll
                for (int mi = 0; mi < MT_W; ++mi) {
                    acc[mi][nj] = __builtin_amdgcn_mfma_f32_16x16x32_f16(ah[mi], bh, acc[mi][nj], 0, 0, 0);
                    acc[mi][nj] = __builtin_amdgcn_mfma_f32_16x16x32_f16(ah[mi], bl, acc[mi][nj], 0, 0, 0);
                    acc[mi][nj] = __builtin_amdgcn_mfma_f32_16x16x32_f16(al[mi], bh, acc[mi][nj], 0, 0, 0);
                }
            }
        }
    }

    int b = bc / CIN, c = bc % CIN;
    #pragma unroll
    for (int mi = 0; mi < MT_W; ++mi) {
        int mt = MT_SPLIT ? (w * MT_W + mi) : mi;
        #pragma unroll
        for (int nj = 0; nj < NT_W; ++nj) {
            int nt = MT_SPLIT ? nj : (w + nj * NT_STRIDE);
            if (nt < NTILES) {
                int j = nt * 16 + col;
                if (j < 2 * F) {
                    int t0 = mt * 16 + quad * 4;
                    f32x4 a = acc[mi][nj];
                    #pragma unroll
                    for (int r = 0; r < 4; ++r) {
                        p[(((size_t)b * TFR + t0 + r) * CIN + c) * (2 * F) + j] = a[r];
                    }
                }
            }
        }
    }
}

// ---------------- init: STFT D tables, B-fragment order, split fp16 ------------
__global__ __launch_bounds__(256)
void init_d_kernel(u16* __restrict__ dhi0, u16* __restrict__ dlo0,
                   u16* __restrict__ dhi1, u16* __restrict__ dlo1) {
    int idx = blockIdx.x * 256 + threadIdx.x;
    constexpr int SZ0 = 5 * 2 * 64 * 8;    // 5120
    constexpr int SZ1 = 17 * 8 * 64 * 8;   // 69632
    int N, F, KTT, id; u16 *dh, *dl;
    if (idx < SZ0)            { N = 64;  F = F0n; KTT = 2; dh = dhi0; dl = dlo0; id = idx; }
    else if (idx < SZ0 + SZ1) { N = 256; F = F1n; KTT = 8; dh = dhi1; dl = dlo1; id = idx - SZ0; }
    else return;
    int jj   = id & 7;
    int lane = (id >> 3) & 63;
    int rest = id >> 9;
    int kt   = rest % KTT;
    int nt   = rest / KTT;
    int j = nt * 16 + (lane & 15);
    int k = kt * 32 + (lane >> 4) * 8 + jj;
    float v = 0.f;
    if (j < 2 * F) {
        int f = j >> 1;
        int u = (f * k) % N;
        double th = 6.283185307179586476925286766559 * (double)u / (double)N;
        v = (float)((j & 1) ? -sin(th) : cos(th));
    }
    _Float16 h = (_Float16)v;
    _Float16 l = (_Float16)(v - (float)h);
    dh[id] = *(u16*)&h;
    dl[id] = *(u16*)&l;
}

// ---------------- merge (attention over 4 sub-frames), in-place into p1 --------
__global__ __launch_bounds__(256)
void merge_kernel(const float2* __restrict__ p0, float2* __restrict__ p1,
                  const float* __restrict__ mkr, const float* __restrict__ mki,
                  const float* __restrict__ mbr, const float* __restrict__ mbi) {
    int idx = blockIdx.x * 256 + threadIdx.x;
    const int total = BB * T1n * CIN * F0n;
    if (idx >= total) return;
    int f0 = idx % F0n; int r1 = idx / F0n;
    int c  = r1 % CIN;  int r2 = r1 / CIN;
    int t1 = r2 % T1n;  int b  = r2 / T1n;
    float2 pm[4];
    #pragma unroll
    for (int r = 0; r < 4; ++r) {
        int t = t1 * 4 + r;
        pm[r] = p0[(((size_t)b * T0n + t) * CIN + c) * F0n + f0];
    }
    float mag[4], mx = -1e30f;
    #pragma unroll
    for (int s = 0; s < 4; ++s) {
        float atr = mbr[s], ati = mbi[s];
        #pragma unroll
        for (int r = 0; r < 4; ++r) {
            float kr = mkr[r * 4 + s], ki = mki[r * 4 + s];
            atr = fmaf(pm[r].x, kr, atr); atr = fmaf(-pm[r].y, ki, atr);
            ati = fmaf(pm[r].x, ki, ati); ati = fmaf(pm[r].y, kr, ati);
        }
        mag[s] = sqrtf(atr * atr + ati * ati);
        mx = fmaxf(mx, mag[s]);
    }
    float se = 0.f;
    #pragma unroll
    for (int s = 0; s < 4; ++s) { mag[s] = expf(mag[s] - mx); se += mag[s]; }
    float inv = 4.0f / se;                 // RATIO / sum
    float mr = 0.f, mi = 0.f;
    #pragma unroll
    for (int r = 0; r < 4; ++r) { mr = fmaf(pm[r].x, mag[r], mr); mi = fmaf(pm[r].y, mag[r], mi); }
    p1[(((size_t)b * T1n + t1) * CIN + c) * F1n + 4 * f0] = make_float2(mr * inv, mi * inv);
}

// ---------------- complex batch-norm stats, two-stage ---------------------------
__global__ __launch_bounds__(256)
void cbn_partial_kernel(const float2* __restrict__ p0, const float2* __restrict__ p1,
                        float4* __restrict__ part) {
    int blk  = blockIdx.x;                 // head*512 + b*8 + c8
    int c8   = blk & 7;
    int b    = (blk >> 3) & 63;
    int head = blk >> 9;
    int Nel  = head ? (T1n * CIN * F1n) : (T0n * CIN * F0n);
    const float2* base = head ? (p1 + (size_t)b * (T1n * CIN * F1n))
                              : (p0 + (size_t)b * (T0n * CIN * F0n));
    int chunk = (Nel + 7) / 8;
    int i0 = c8 * chunk, i1 = imin(i0 + chunk, Nel);
    float sr = 0.f, si = 0.f, s2 = 0.f;
    for (int i = i0 + threadIdx.x; i < i1; i += 256) {
        float2 v = base[i];
        sr += v.x; si += v.y;
        s2 = fmaf(v.x, v.x, s2); s2 = fmaf(v.y, v.y, s2);
    }
    __shared__ float red[3][256];
    red[0][threadIdx.x] = sr; red[1][threadIdx.x] = si; red[2][threadIdx.x] = s2;
    __syncthreads();
    for (int off = 128; off > 0; off >>= 1) {
        if (threadIdx.x < off) {
            red[0][threadIdx.x] += red[0][threadIdx.x + off];
            red[1][threadIdx.x] += red[1][threadIdx.x + off];
            red[2][threadIdx.x] += red[2][threadIdx.x + off];
        }
        __syncthreads();
    }
    if (threadIdx.x == 0)
        part[blk] = make_float4(red[0][0], red[1][0], red[2][0], 0.f);
}

__global__ __launch_bounds__(128)
void cbn_final_kernel(const float4* __restrict__ part,
                      const float* __restrict__ gamma, const float* __restrict__ beta,
                      float4* __restrict__ bn) {
    int hb = threadIdx.x;                  // 0..127 = head*64 + b
    float sr = 0.f, si = 0.f, s2 = 0.f;
    #pragma unroll
    for (int c = 0; c < 8; ++c) {
        float4 v = part[hb * 8 + c];
        sr += v.x; si += v.y; s2 += v.z;
    }
    int head = hb >> 6;
    int Nel  = head ? (T1n * CIN * F1n) : (T0n * CIN * F0n);
    float invN = 1.f / (float)Nel;
    float mur = sr * invN, mui = si * invN;
    float var = s2 * invN - mur * mur - mui * mui;
    float g = gamma[hb] * rsqrtf(var + 1e-5f);
    bn[hb] = make_float4(g, beta[hb] - mur * g, -mui * g, 0.f);
}

// ---------------- init: irfft twiddle matrix (HALF rows m < N/2), split fp16 ---
__global__ __launch_bounds__(256)
void init_w_kernel(u16* __restrict__ whi0, u16* __restrict__ wlo0,
                   u16* __restrict__ whi1, u16* __restrict__ wlo1) {
    int idx = blockIdx.x * 256 + threadIdx.x;
    constexpr int SZ0 = 2 * 3 * 64 * 8;    // 3072
    constexpr int SZ1 = 8 * 9 * 64 * 8;    // 36864
    int N, F, KT, id; u16 *dh, *dl;
    if (idx < SZ0)            { N = 64;  F = F0n; KT = 3; dh = whi0; dl = wlo0; id = idx; }
    else if (idx < SZ0 + SZ1) { N = 256; F = F1n; KT = 9; dh = whi1; dl = wlo1; id = idx - SZ0; }
    else return;
    int j    = id & 7;
    int lane = (id >> 3) & 63;
    int rest = id >> 9;
    int kt   = rest % KT;
    int mt   = rest / KT;
    int m  = mt * 16 + (lane & 15);        // m < N/2 only
    int k2 = kt * 32 + (lane >> 4) * 8 + j;
    float v = 0.f;
    if (k2 < 2 * F) {
        int f = k2 >> 1;
        double scale = (f == 0 || f == F - 1) ? (1024.0 / N) : (2048.0 / N);
        int u = (m * f) % N;
        double th = 6.283185307179586476925286766559 * (double)u / (double)N;
        v = (float)((k2 & 1) ? (-scale * sin(th)) : (scale * cos(th)));
    }
    _Float16 h = (_Float16)v;
    _Float16 l = (_Float16)(v - (float)h);
    dh[id] = *(u16*)&h;
    dl[id] = *(u16*)&l;
}

// ---------------- init: fk tables, layout i = o*F + f --------------------------
// fkq[c2*FCO + o*F + f] = (kr(f,2c2,o), ki(f,2c2,o), kr(f,2c2+1,o), ki(f,2c2+1,o))
// fks[o*F + f] = sum_ci (kr, ki)
__global__ __launch_bounds__(256)
void init_fk_kernel(const float* __restrict__ r0, const float* __restrict__ i0,
                    const float* __restrict__ r1, const float* __restrict__ i1,
                    float4* __restrict__ q0, float4* __restrict__ q1,
                    float2* __restrict__ s0, float2* __restrict__ s1) {
    int idx = blockIdx.x * 256 + threadIdx.x;
    constexpr int NQ0 = 8 * F0n * 32;   // 8448
    constexpr int NQ1 = 8 * F1n * 32;   // 33024
    constexpr int NS0 = F0n * 32;       // 1056
    constexpr int NS1 = F1n * 32;       // 4128
    if (idx < NQ0) {
        int id = idx;
        int c2 = id / (F0n * 32); int rem = id % (F0n * 32);
        int o = rem / F0n, f = rem % F0n;
        int s = (f * CIN + 2 * c2) * CO + o;
        q0[id] = make_float4(r0[s], i0[s], r0[s + CO], i0[s + CO]);
    } else if (idx < NQ0 + NQ1) {
        int id = idx - NQ0;
        int c2 = id / (F1n * 32); int rem = id % (F1n * 32);
        int o = rem / F1n, f = rem % F1n;
        int s = (f * CIN + 2 * c2) * CO + o;
        q1[id] = make_float4(r1[s], i1[s], r1[s + CO], i1[s + CO]);
    } else if (idx < NQ0 + NQ1 + NS0) {
        int id = idx - NQ0 - NQ1;
        int o = id / F0n, f = id % F0n;
        float sr = 0.f, si = 0.f;
        for (int ci = 0; ci < CIN; ++ci) {
            int s = (f * CIN + ci) * CO + o;
            sr += r0[s]; si += i0[s];
        }
        s0[id] = make_float2(sr, si);
    } else if (idx < NQ0 + NQ1 + NS0 + NS1) {
        int id = idx - NQ0 - NQ1 - NS0;
        int o = id / F1n, f = id % F1n;
        float sr = 0.f, si = 0.f;
        for (int ci = 0; ci < CIN; ++ci) {
            int s = (f * CIN + ci) * CO + o;
            sr += r1[s]; si += i1[s];
        }
        s1[id] = make_float2(sr, si);
    }
}

// ---------------- einsum: weights-in-VGPR, t-chunked grid ----------------------
// Block = (f-chunk FCH=8, t-chunk TCH=16, b); one LDS batch per block.
// Round-6 lesson: the streaming form at 320/1088 blocks = 1 block/CU = 1
// wave/SIMD -> all latency exposed (VALUBusy 18%, occ 10%).  t-chunking gives
// 2560/2176 blocks (~8-10/CU, 32 waves/CU); fkq re-reads stay L2-hot (<530KB).
// Thread (o, f') holds its 8 fkq float4 in VGPRs.  Writes packed split-f16 S:
//   Ghi[(bt*32+o)*F + f] = ih<<16|rh,  Glo = il<<16|rl  (row stride F, no pad)
template<int F, int TFR, int CH0, int FCH, int TCH>
__global__ __launch_bounds__(256)
void einsum_kernel(const float2* __restrict__ p, const float4* __restrict__ fkq,
                   const float2* __restrict__ fks, const float4* __restrict__ bn,
                   uint32* __restrict__ Ghi, uint32* __restrict__ Glo) {
    constexpr int FCO  = F * 32;
    constexpr int NFCH = (F + FCH - 1) / FCH;
    constexpr int NTC  = TFR / TCH;
    static_assert(FCH == 8 && TCH * CIN * FCH % 256 == 0, "cfg");
    __shared__ float2 xs[TCH][CIN][FCH];
    int blk  = blockIdx.x;
    int fch  = blk % NFCH;
    int rest = blk / NFCH;
    int tc   = rest % NTC;
    int b    = rest / NTC;
    int t0   = tc * TCH;
    int f0   = fch * FCH;
    int o    = threadIdx.x >> 3;       // 0..31
    int fl   = threadIdx.x & 7;        // 0..7
    int f    = f0 + fl;
    bool valid = f < F;
    int fc = valid ? f : F - 1;
    float4 kk[8];
    #pragma unroll
    for (int c2 = 0; c2 < 8; ++c2) kk[c2] = fkq[c2 * FCO + o * F + fc];  // coalesced 128B runs
    float2 fv = fks[o * F + fc];
    float4 par = bn[(CH0 ? 1 : 0) * BB + b];   // (g, t_re, t_im, -)
    float base_re = fmaf(par.y, fv.x, -par.z * fv.y);
    float base_im = fmaf(par.y, fv.y,  par.z * fv.x);

    const float2* pb = p + (size_t)(b * TFR + t0) * CIN * F;
    for (int i = threadIdx.x; i < TCH * CIN * FCH; i += 256) {
        int fi = i & 7;                // FCH = 8
        int r  = i >> 3;               // t'*CIN + ci
        int ff = f0 + fi;
        ((float2*)xs)[i] = (ff < F) ? pb[(size_t)r * F + ff] : make_float2(0.f, 0.f);
    }
    __syncthreads();
    for (int tp = 0; tp < TCH; ++tp) {
        float re = 0.f, im = 0.f;
        #pragma unroll
        for (int c2 = 0; c2 < 8; ++c2) {
            float2 xa = xs[tp][2 * c2][fl];        // LDS broadcast (8 lanes/addr)
            float2 xb = xs[tp][2 * c2 + 1][fl];
            float4 kkc = kk[c2];
            re = fmaf(xa.x, kkc.x, re); re = fmaf(-xa.y, kkc.y, re);
            im = fmaf(xa.x, kkc.y, im); im = fmaf(xa.y, kkc.x, im);
            re = fmaf(xb.x, kkc.z, re); re = fmaf(-xb.y, kkc.w, re);
            im = fmaf(xb.x, kkc.w, im); im = fmaf(xb.y, kkc.z, im);
        }
        if (valid) {
            float res = fmaf(par.x, re, base_re) * 32.f;
            float ims = fmaf(par.x, im, base_im) * 32.f;
            _Float16 rh = (_Float16)res; _Float16 rl = (_Float16)(res - (float)rh);
            _Float16 ih = (_Float16)ims; _Float16 il = (_Float16)(ims - (float)ih);
            size_t d = ((size_t)(b * TFR + t0 + tp) * 32 + o) * F + f;
            Ghi[d] = ((uint32)(*(u16*)&ih) << 16) | (uint32)(*(u16*)&rh);
            Glo[d] = ((uint32)(*(u16*)&il) << 16) | (uint32)(*(u16*)&rl);
        }
    }
}

// ---------------- irfft: per-frame blocks, copy staging, W row-symmetry --------
// grid: B*(TFR+1); frame TFR re-uses S of frame 0 (wrap frame).
// Stage = pure dword copy (S already packed split-f16 by einsum) + LDS zero-pad
// of columns [F, KT*16).  LDS rows LDW=KT*16+4 dwords (2-way bank alias, free).
template<int N, int F, int TFR, int CH0, int KT, int WMT, bool NTSPLIT>
__global__ __launch_bounds__(256)
void irfft_kernel(const uint32* __restrict__ Ghi, const uint32* __restrict__ Glo,
                  const u16* __restrict__ whi, const u16* __restrict__ wlo,
                  const float* __restrict__ pbias, float* __restrict__ out) {
    constexpr int PADW = KT * 16;
    constexpr int LDW  = PADW + 4;
    constexpr int WNT  = NTSPLIT ? 1 : 2;
    __shared__ __align__(16) uint32 buf[2][32 * LDW];
    int t  = blockIdx.x % (TFR + 1);
    int b  = blockIdx.x / (TFR + 1);
    int tf = (t == TFR) ? 0 : t;
    const uint32* sH = Ghi + (size_t)(b * TFR + tf) * 32 * F;
    const uint32* sL = Glo + (size_t)(b * TFR + tf) * 32 * F;
    for (int i = threadIdx.x; i < 32 * F; i += 256) {
        int row = i / F, c = i - row * F;
        buf[0][row * LDW + c] = sH[i];
        buf[1][row * LDW + c] = sL[i];
    }
    for (int i = threadIdx.x; i < 32 * (PADW - F); i += 256) {
        constexpr int cols = PADW - F;
        int row = i / cols, c = i - row * cols;
        buf[0][row * LDW + F + c] = 0;
        buf[1][row * LDW + F + c] = 0;
    }
    __syncthreads();

    int lane = threadIdx.x & 63, w = threadIdx.x >> 6;
    int col = lane & 15, quad = lane >> 4;
    const u16* bufh = (const u16*)&buf[0][0];
    const u16* bufl = (const u16*)&buf[1][0];

    f32x4 accB[WMT][WNT], accD[WMT][WNT];   // base rows m, derived rows m+N/2
    #pragma unroll
    for (int mi = 0; mi < WMT; ++mi)
        #pragma unroll
        for (int nj = 0; nj < WNT; ++nj) {
            f32x4 z = {0.f, 0.f, 0.f, 0.f};
            accB[mi][nj] = z; accD[mi][nj] = z;
        }
    for (int kt = 0; kt < KT; ++kt) {
        half8 bh[WNT], bl[WNT], bhm[WNT], blm[WNT];
        #pragma unroll
        for (int nj = 0; nj < WNT; ++nj) {
            int nt = NTSPLIT ? (w & 1) : nj;
            int ro = (nt * 16 + col) * (2 * LDW) + kt * 32 + quad * 8;
            bh[nj]  = *(const half8*)(bufh + ro);
            bl[nj]  = *(const half8*)(bufl + ro);
            bhm[nj] = flip_pm(bh[nj]);
            blm[nj] = flip_pm(bl[nj]);
        }
        #pragma unroll
        for (int mi = 0; mi < WMT; ++mi) {
            int mt = NTSPLIT ? (w >> 1) : (w * WMT + mi);
            half8 ah = ((const half8*)whi)[(mt * KT + kt) * 64 + lane];
            half8 al = ((const half8*)wlo)[(mt * KT + kt) * 64 + lane];
            #pragma unroll
            for (int nj = 0; nj < WNT; ++nj) {
                accB[mi][nj] = __builtin_amdgcn_mfma_f32_16x16x32_f16(ah, bh[nj],  accB[mi][nj], 0, 0, 0);
                accB[mi][nj] = __builtin_amdgcn_mfma_f32_16x16x32_f16(ah, bl[nj],  accB[mi][nj], 0, 0, 0);
                accB[mi][nj] = __builtin_amdgcn_mfma_f32_16x16x32_f16(al, bh[nj],  accB[mi][nj], 0, 0, 0);
                accD[mi][nj] = __builtin_amdgcn_mfma_f32_16x16x32_f16(ah, bhm[nj], accD[mi][nj], 0, 0, 0);
                accD[mi][nj] = __builtin_amdgcn_mfma_f32_16x16x32_f16(ah, blm[nj], accD[mi][nj], 0, 0, 0);
                accD[mi][nj] = __builtin_amdgcn_mfma_f32_16x16x32_f16(al, bhm[nj], accD[mi][nj], 0, 0, 0);
            }
        }
    }
    constexpr float UNSCALE = 1.0f / 32768.0f;   // 2^-15 (W*2^10, S*2^5)
    size_t bb = (size_t)b * TCO;
    #pragma unroll
    for (int mi = 0; mi < WMT; ++mi) {
        int mt = NTSPLIT ? (w >> 1) : (w * WMT + mi);
        #pragma unroll
        for (int hh = 0; hh < 2; ++hh) {
            int m  = mt * 16 + quad * 4 + hh * (N / 2);
            int l0 = t * N + m - N / 2;
            if ((unsigned)l0 < LL) {
                #pragma unroll
                for (int nj = 0; nj < WNT; ++nj) {
                    int nt = NTSPLIT ? (w & 1) : nj;
                    int chn = CH0 + nt * 16 + col;
                    float pb = pbias[chn];
                    f32x4 a = hh ? accD[mi][nj] : accB[mi][nj];
                    float4 v;
                    v.x = fmaxf(fmaf(a[0], UNSCALE, pb), 0.f);
                    v.y = fmaxf(fmaf(a[1], UNSCALE, pb), 0.f);
                    v.z = fmaxf(fmaf(a[2], UNSCALE, pb), 0.f);
                    v.w = fmaxf(fmaf(a[3], UNSCALE, pb), 0.f);
                    *(float4*)(out + (bb + chn) * LL + l0) = v;
                }
            }
        }
    }
}

extern "C" void kernel_launch(void* const* d_in, const int* in_sizes, int n_in,
                              void* d_out, int out_size, void* d_ws, size_t ws_size,
                              hipStream_t stream) {
    const float* x     = (const float*)d_in[0];
    const float* gam   = (const float*)d_in[1];
    const float* bet   = (const float*)d_in[2];
    const float* mkr   = (const float*)d_in[3];
    const float* mki   = (const float*)d_in[4];
    const float* mbr   = (const float*)d_in[5];
    const float* mbi   = (const float*)d_in[6];
    const float* fk0r  = (const float*)d_in[7];
    const float* fk0i  = (const float*)d_in[8];
    const float* fk1r  = (const float*)d_in[9];
    const float* fk1i  = (const float*)d_in[10];
    const float* pbias = (const float*)d_in[11];
    float* out = (float*)d_out;

    float2* p0   = (float2*)d_ws;                                   // 34.6 MB
    float2* p1   = p0 + (size_t)BB * T0n * CIN * F0n;               // 33.8 MB
    float4* bnp  = (float4*)(p1 + (size_t)BB * T1n * CIN * F1n);    // 2 KB
    float4* part = bnp + 2 * BB;                                    // 16 KB
    float4* fkq0 = part + 1024;                                     // 135 KB
    float4* fkq1 = fkq0 + 8 * F0n * 32;                             // 528 KB
    float2* fks0 = (float2*)(fkq1 + 8 * F1n * 32);                  // 8 KB
    float2* fks1 = fks0 + F0n * 32;                                 // 33 KB
    // S buffers: sized for the larger head (head0: 64*128*32*33 dwords = 34.6 MB)
    uint32* Ghi  = (uint32*)(fks1 + F1n * 32);
    uint32* Glo  = Ghi + (size_t)BB * T0n * 32 * F0n;
    u16*    whi0 = (u16*)(Glo + (size_t)BB * T0n * 32 * F0n);       // 6 KB
    u16*    wlo0 = whi0 + 3072;
    u16*    whi1 = wlo0 + 3072;                                     // 72 KB
    u16*    wlo1 = whi1 + 36864;
    u16*    dhi0 = wlo1 + 36864;                                    // 10 KB
    u16*    dlo0 = dhi0 + 5120;
    u16*    dhi1 = dlo0 + 5120;                                     // 139 KB
    u16*    dlo1 = dhi1 + 69632;

    init_w_kernel<<<(3072 + 36864 + 255) / 256, 256, 0, stream>>>(whi0, wlo0, whi1, wlo1);
    init_d_kernel<<<(5120 + 69632 + 255) / 256, 256, 0, stream>>>(dhi0, dlo0, dhi1, dlo1);
    init_fk_kernel<<<(8 * (F0n + F1n) * 32 + (F0n + F1n) * 32 + 255) / 256, 256, 0, stream>>>(
        fk0r, fk0i, fk1r, fk1i, fkq0, fkq1, fks0, fks1);
    stft_mfma_kernel<64, F0n, 128, 5, 2, 2, 5, 1, true><<<BB * CIN, 256, 0, stream>>>(
        x, dhi0, dlo0, (float*)p0);
    stft_mfma_kernel<256, F1n, 32, 17, 8, 2, 5, 4, false><<<BB * CIN, 256, 0, stream>>>(
        x, dhi1, dlo1, (float*)p1);
    merge_kernel<<<(BB * T1n * CIN * F0n) / 256, 256, 0, stream>>>(p0, p1, mkr, mki, mbr, mbi);
    cbn_partial_kernel<<<1024, 256, 0, stream>>>(p0, p1, part);
    cbn_final_kernel<<<1, 128, 0, stream>>>(part, gam, bet, bnp);
    // head1 then head0, sharing Ghi/Glo (stream order makes reuse safe)
    einsum_kernel<F1n, T1n, 32, 8, 16><<<17 * 2 * BB, 256, 0, stream>>>(
        p1, fkq1, fks1, bnp, Ghi, Glo);
    irfft_kernel<256, F1n, T1n, 32, 9, 2, false><<<BB * (T1n + 1), 256, 0, stream>>>(
        Ghi, Glo, whi1, wlo1, pbias, out);
    einsum_kernel<F0n, T0n, 0, 8, 16><<<5 * 8 * BB, 256, 0, stream>>>(
        p0, fkq0, fks0, bnp, Ghi, Glo);
    irfft_kernel<64, F0n, T0n, 0, 3, 1, true><<<BB * (T0n + 1), 256, 0, stream>>>(
        Ghi, Glo, whi0, wlo0, pbias, out);
}